// Round 19
// baseline (91.202 us; speedup 1.0000x reference)
//
#include <hip/hip_runtime.h>

#define HW   4096
#define Hh   64
#define Ww   64
#define NB   27
#define EPSBN 1e-5f

typedef _Float16 f16x8 __attribute__((ext_vector_type(8)));
typedef _Float16 f16x4 __attribute__((ext_vector_type(4)));
typedef _Float16 f16x2 __attribute__((ext_vector_type(2)));
typedef float    f32x4 __attribute__((ext_vector_type(4)));

// async global->LDS, 16B per lane; LDS dest = wave-uniform base + lane*16
__device__ __forceinline__ void gld_lds16(const void* g, void* l) {
    __builtin_amdgcn_global_load_lds(
        (const __attribute__((address_space(1))) unsigned int*)g,
        (__attribute__((address_space(3))) unsigned int*)l, 16, 0, 0);
}

// ---------------------------------------------------------------------------
// prep: x (b,c,p) f32 -> xT (b,p,c) f16 via LDS transpose (proven R8/R9 code;
// pad-516 rows keep both phases bank-safe; both global sides coalesced).
// 256 blocks x 256 thr; block t: batch t>>6, 64-px chunk (t&63)*64.
// ---------------------------------------------------------------------------
__global__ __launch_bounds__(256)
void prep_x(const float* __restrict__ x, _Float16* __restrict__ xT)
{
    __shared__ _Float16 T[64][516];
    const int t  = blockIdx.x;
    const int p0 = (t & 63) * 64;
    const int b  = t >> 6;
    const int tx = threadIdx.x & 63;
    const int ty = threadIdx.x >> 6;

    #pragma unroll 2
    for (int ch = 0; ch < 16; ++ch) {
        const int c0 = ch * 32 + ty * 8;
        const float* xp = x + ((size_t)b * 512 + c0) * HW + p0 + tx;
        f16x8 h;
        #pragma unroll
        for (int i = 0; i < 8; ++i) h[i] = (_Float16)xp[(size_t)i * HW];
        *(f16x8*)&T[tx][c0] = h;
    }
    __syncthreads();
    #pragma unroll 4
    for (int rr = 0; rr < 16; ++rr) {
        const int row = rr * 4 + ty;
        f16x8 h = *(const f16x8*)&T[row][tx * 8];
        *(f16x8*)(xT + ((size_t)b * HW + p0 + row) * 512 + tx * 8) = h;
    }
}

// ---------------------------------------------------------------------------
// R19 GEMM — ONE unified loop (counted-vmcnt gld_lds pipeline, proven R18):
// per tile t: issue A(t+1) f32 reg-loads + B(t+2) gld_lds -> MFMA(t) ->
// WRITE_A (compiler auto-waits ar deps with vmcnt(4), leaving B(t+2)'s 4
// gld_lds in flight) -> asm vmcnt(4)+lgkmcnt(0) -> raw s_barrier ->
// sched_barrier(0) (rule 18). B(t+2) crosses the barrier in flight (T4).
// Stage 1 now consumes f16 xT like stages 2/4 (prep_x above): B staging is
// 4 gld_lds/wave/tile instead of 32 scalar f32 dwords/thread (R18 stage-1),
// halving bytes and cutting VMEM instrs ~8x; the f32-B register path (R17's
// spill hazard) is deleted entirely.
// Shared-B: nA A-slots (64 rows) per staged 256px x 64k B tile (~140 FLOP/B
// at f16 x). XOR swizzle (byte ^= (row&7)<<4) write+read. Block-uniform
// VALUE job selects (R3 lesson). mode: 0=f16 out (p,c); 2=f32 out (b,c,p).
// ---------------------------------------------------------------------------
struct GJob {
    const _Float16* in;   // (16384, K) f16
    const float*    w;    // (O, K) f32 original weights
    const float* b; const float* g; const float* be; const float* m; const float* v;
    _Float16* oh;
    float*    of;
};

__global__ __launch_bounds__(512, 1)
void gemm_f(GJob J0, GJob J1, GJob J2, int stage, int K, int JO, int mode)
{
    __shared__ _Float16 As[2][3][4096];   // 2 buf x 3 slots x 8KB = 48 KB
    __shared__ _Float16 Bs[3][16384];     // 3 buf x 32KB (256 px x 64 k)

    const int tid  = threadIdx.x;
    const int lane = tid & 63;
    const int w8   = tid >> 6;            // wave 0..7
    const int lr   = lane & 15;
    const int lg   = lane >> 4;
    const int wq   = w8 & 3;              // 16-row quarter of each 64-row slot
    const int ph   = w8 >> 2;             // 128-px half of the 256-px tile

    const int bid = blockIdx.x;           // 256 blocks = 1/CU
    const int xcd = bid & 7;
    const int jj  = bid >> 3;             // 0..31
    const int nb  = xcd * 8 + (jj >> 2);  // 256-px chunk 0..63 (XCD-local)
    const int u   = jj & 3;

    const int nA = (stage == 1) ? 3 : 2;
    int js0, js1, js2, ob0, ob1, ob2;
    if (stage == 1)      { js0 = 0; js1 = 1; js2 = 2; ob0 = ob1 = ob2 = u * 64; }
    else if (stage == 2) { js0 = js1 = js2 = (u >> 1); ob0 = (u & 1) * 128; ob1 = ob0 + 64; ob2 = ob1; }
    else                 { js0 = js1 = js2 = 0; ob0 = u * 128; ob1 = ob0 + 64; ob2 = ob1; }

#define JSEL(js, f) ((js) == 0 ? J0.f : ((js) == 1 ? J1.f : J2.f))
    const float* w0 = JSEL(js0, w);
    const float* w1 = JSEL(js1, w);
    const float* w2 = JSEL(js2, w);
    const float* b0 = JSEL(js0, b); const float* g0 = JSEL(js0, g);
    const float* be0 = JSEL(js0, be); const float* m0 = JSEL(js0, m); const float* v0 = JSEL(js0, v);
    const float* b1 = JSEL(js1, b); const float* g1 = JSEL(js1, g);
    const float* be1 = JSEL(js1, be); const float* m1 = JSEL(js1, m); const float* v1 = JSEL(js1, v);
    const float* b2 = JSEL(js2, b); const float* g2 = JSEL(js2, g);
    const float* be2 = JSEL(js2, be); const float* m2 = JSEL(js2, m); const float* v2 = JSEL(js2, v);
    _Float16* oh0 = JSEL(js0, oh); float* of0 = JSEL(js0, of);
    _Float16* oh1 = JSEL(js1, oh); float* of1 = JSEL(js1, of);
    _Float16* oh2 = JSEL(js2, oh); float* of2 = JSEL(js2, of);
    const _Float16* bIn = JSEL(js0, in);
#undef JSEL

    // A f32 staging: lane covers row rowA, 8 cols at scol (pre-swizzled,
    // rule #21) -> LDS byte image identical to a gld_lds f16 path.
    const int scol = (((lane & 7) ^ (lane >> 3)) << 3);
    const int rowA = w8 * 8 + (lane >> 3);
    const float* aS0 = w0 + (size_t)(ob0 + rowA) * K + scol;
    const float* aS1 = w1 + (size_t)(ob1 + rowA) * K + scol;
    const float* aS2 = w2 + (size_t)(ob2 + rowA) * K + scol;
    const int aoffW  = w8 * 1024 + lane * 16;

    // B f16 staging: wave w8 covers rows w8*32 + j*8 + lane/8, j=0..3
    const int rowB = w8 * 32 + (lane >> 3);
    const _Float16* bS = bIn + (size_t)(nb * 256 + rowB) * K + scol;

    float ar0[8], ar1[8], ar2[8];              // A staging regs

    auto ISSUE_A = [&](int rd) {
        const int kb = rd * 64;
        *(float4*)&ar0[0] = *(const float4*)(aS0 + kb);
        *(float4*)&ar0[4] = *(const float4*)(aS0 + kb + 4);
        *(float4*)&ar1[0] = *(const float4*)(aS1 + kb);
        *(float4*)&ar1[4] = *(const float4*)(aS1 + kb + 4);
        if (nA > 2) {
            *(float4*)&ar2[0] = *(const float4*)(aS2 + kb);
            *(float4*)&ar2[4] = *(const float4*)(aS2 + kb + 4);
        }
    };
    auto WRITE_A = [&](int buf) {
        f16x8 h0, h1, h2;
        #pragma unroll
        for (int i2 = 0; i2 < 8; ++i2) h0[i2] = (_Float16)ar0[i2];
        #pragma unroll
        for (int i2 = 0; i2 < 8; ++i2) h1[i2] = (_Float16)ar1[i2];
        *(f16x8*)((char*)&As[buf][0][0] + aoffW) = h0;
        *(f16x8*)((char*)&As[buf][1][0] + aoffW) = h1;
        if (nA > 2) {
            #pragma unroll
            for (int i2 = 0; i2 < 8; ++i2) h2[i2] = (_Float16)ar2[i2];
            *(f16x8*)((char*)&As[buf][2][0] + aoffW) = h2;
        }
    };
    auto STAGE_B16 = [&](int buf, int rd) {    // 4 gld_lds per wave
        const int kb = rd * 64;
        #pragma unroll
        for (int j2 = 0; j2 < 4; ++j2)
            gld_lds16(bS + (size_t)j2 * 8 * K + kb, (char*)&Bs[buf][0] + w8 * 4096 + j2 * 1024);
    };

    f32x4 acc0[8] = {}, acc1[8] = {}, acc2[8] = {};
    const int nr = K >> 6;

    auto MFMA_TILE = [&](int bb, int ab) {
        #pragma unroll
        for (int ks = 0; ks < 2; ++ks) {
            const int colx = (ks * 64 + lg * 16) ^ ((lr & 7) << 4);
            f16x8 bfr[8];
            #pragma unroll
            for (int t = 0; t < 8; ++t)
                bfr[t] = *(const f16x8*)((const char*)&Bs[bb][0] + (ph * 128 + t * 16 + lr) * 128 + colx);
            const int aoff = (wq * 16 + lr) * 128 + colx;
            const f16x8 af0 = *(const f16x8*)((const char*)&As[ab][0][0] + aoff);
            const f16x8 af1 = *(const f16x8*)((const char*)&As[ab][1][0] + aoff);
            #pragma unroll
            for (int t = 0; t < 8; ++t)
                acc0[t] = __builtin_amdgcn_mfma_f32_16x16x32_f16(af0, bfr[t], acc0[t], 0, 0, 0);
            #pragma unroll
            for (int t = 0; t < 8; ++t)
                acc1[t] = __builtin_amdgcn_mfma_f32_16x16x32_f16(af1, bfr[t], acc1[t], 0, 0, 0);
            if (nA > 2) {
                const f16x8 af2 = *(const f16x8*)((const char*)&As[ab][2][0] + aoff);
                #pragma unroll
                for (int t = 0; t < 8; ++t)
                    acc2[t] = __builtin_amdgcn_mfma_f32_16x16x32_f16(af2, bfr[t], acc2[t], 0, 0, 0);
            }
        }
    };

    // ---- counted-vmcnt gld_lds pipeline, 3-deep B (proven R18) ----
    STAGE_B16(0, 0);                   // B(0) oldest
    ISSUE_A(0);
    STAGE_B16(1, 1);                   // B(1) youngest (nr>=4 always)
    WRITE_A(0);                        // compiler auto-waits ar deps
    asm volatile("s_waitcnt vmcnt(4) lgkmcnt(0)" ::: "memory");  // B(0)+A ok
    __builtin_amdgcn_s_barrier();
    __builtin_amdgcn_sched_barrier(0);

    for (int rd = 0; rd < nr; ++rd) {
        const bool m1 = (rd + 1 < nr);
        const bool m2 = (rd + 2 < nr);
        if (m1) ISSUE_A(rd + 1);
        if (m2) STAGE_B16((rd + 2) % 3, rd + 2);
        MFMA_TILE(rd % 3, rd & 1);
        if (m1) WRITE_A((rd + 1) & 1); // compiler auto-waits ar deps
        if (m2) asm volatile("s_waitcnt vmcnt(4) lgkmcnt(0)" ::: "memory");
        else    asm volatile("s_waitcnt vmcnt(0) lgkmcnt(0)" ::: "memory");
        __builtin_amdgcn_s_barrier();
        __builtin_amdgcn_sched_barrier(0);
    }

    // epilogue per slot (BN fold + optional ReLU + store)
#define EPI(accS, obS, bS_, gS, beS, mS, vS, ohS, ofS) do {                      \
        const int o4 = (obS) + wq * 16 + lg * 4;                                 \
        float sc[4], off[4];                                                     \
        _Pragma("unroll")                                                        \
        for (int r = 0; r < 4; ++r) {                                            \
            const int o = o4 + r;                                                \
            if (gS) { float s = (gS)[o] * rsqrtf((vS)[o] + EPSBN);               \
                      sc[r] = s; off[r] = fmaf((bS_)[o] - (mS)[o], s, (beS)[o]); }\
            else    { sc[r] = 1.f; off[r] = (bS_)[o]; }                          \
        }                                                                        \
        _Pragma("unroll")                                                        \
        for (int t = 0; t < 8; ++t) {                                            \
            const int pg = nb * 256 + ph * 128 + t * 16 + lr;                    \
            float vv[4];                                                         \
            _Pragma("unroll")                                                    \
            for (int r = 0; r < 4; ++r) {                                        \
                float tv = fmaf(accS[t][r], sc[r], off[r]);                      \
                vv[r] = (gS) ? fmaxf(tv, 0.f) : tv;                              \
            }                                                                    \
            if (mode == 0) {                                                     \
                f16x4 hh;                                                        \
                _Pragma("unroll")                                                \
                for (int r = 0; r < 4; ++r) hh[r] = (_Float16)vv[r];             \
                *(f16x4*)((ohS) + (size_t)pg * JO + o4) = hh;                    \
            } else {                                                             \
                _Pragma("unroll")                                                \
                for (int r = 0; r < 4; ++r)                                      \
                    (ofS)[((size_t)(pg >> 12) * JO + o4 + r) * HW + (pg & 4095)] = vv[r]; \
            }                                                                    \
        }                                                                        \
    } while (0)

    EPI(acc0, ob0, b0, g0, be0, m0, v0, oh0, of0);
    EPI(acc1, ob1, b1, g1, be1, m1, v1, oh1, of1);
    if (nA > 2) EPI(acc2, ob2, b2, g2, be2, m2, v2, oh2, of2);
#undef EPI
}

// ---------------------------------------------------------------------------
// Fused attention: sim + softmax + PV, all buffers (b,p,256) f16.
// Thread = (pixel, 8-ch slot); 32 consecutive lanes read one 512B neighbor
// row coalesced. fdot2 sim partials; shfl_xor reduce over 32 slot-lanes;
// in-register softmax; OOB zeroed via valf (matches zero-padded unfold).
// ---------------------------------------------------------------------------
__global__ __launch_bounds__(256)
void attn_fused(const _Float16* __restrict__ keyT, const _Float16* __restrict__ qryT,
                const _Float16* __restrict__ valT, _Float16* __restrict__ ctxT)
{
    const int tid  = threadIdx.x;
    const int slot = tid & 31;
    const int b    = blockIdx.y;
    const int p    = blockIdx.x * 8 + (tid >> 5);
    const int y    = p >> 6;
    const int xc   = p & 63;

    int   idx[NB];
    float valf[NB];
    #pragma unroll
    for (int n = 0; n < NB; ++n) {
        const int d  = (n < 9) ? 1 : (n < 18 ? 2 : 4);
        const int i  = (n / 3) % 3 - 1;
        const int j  = n % 3 - 1;
        const int yy = y + i * d, xx = xc + j * d;
        const bool ok = ((unsigned)yy < (unsigned)Hh) && ((unsigned)xx < (unsigned)Ww);
        idx[n]  = min(max(yy, 0), Hh - 1) * Ww + min(max(xx, 0), Ww - 1);
        valf[n] = ok ? 1.f : 0.f;
    }

    const size_t base = (size_t)b * HW * 256 + slot * 8;
    const f16x8 q8 = *(const f16x8*)(qryT + base + (size_t)p * 256);

    f16x2 qp[4];
    qp[0] = __builtin_shufflevector(q8, q8, 0, 1);
    qp[1] = __builtin_shufflevector(q8, q8, 2, 3);
    qp[2] = __builtin_shufflevector(q8, q8, 4, 5);
    qp[3] = __builtin_shufflevector(q8, q8, 6, 7);

    float sim[NB];
    #pragma unroll
    for (int n = 0; n < NB; ++n) {
        const f16x8 k8 = *(const f16x8*)(keyT + base + (size_t)idx[n] * 256);
        float s = 0.f;
        s = __builtin_amdgcn_fdot2(__builtin_shufflevector(k8, k8, 0, 1), qp[0], s, false);
        s = __builtin_amdgcn_fdot2(__builtin_shufflevector(k8, k8, 2, 3), qp[1], s, false);
        s = __builtin_amdgcn_fdot2(__builtin_shufflevector(k8, k8, 4, 5), qp[2], s, false);
        s = __builtin_amdgcn_fdot2(__builtin_shufflevector(k8, k8, 6, 7), qp[3], s, false);
        sim[n] = s;
    }

    #pragma unroll
    for (int n = 0; n < NB; ++n) {
        float s = sim[n];
        s += __shfl_xor(s, 1);
        s += __shfl_xor(s, 2);
        s += __shfl_xor(s, 4);
        s += __shfl_xor(s, 8);
        s += __shfl_xor(s, 16);
        sim[n] = s * valf[n];
    }

    float mx = sim[0];
    #pragma unroll
    for (int n = 1; n < NB; ++n) mx = fmaxf(mx, sim[n]);
    float sum = 0.f;
    #pragma unroll
    for (int n = 0; n < NB; ++n) { sim[n] = __expf(sim[n] - mx); sum += sim[n]; }
    const float inv = 1.f / sum;
    #pragma unroll
    for (int n = 0; n < NB; ++n) sim[n] = sim[n] * inv * valf[n];

    float acc[8];
    #pragma unroll
    for (int i = 0; i < 8; ++i) acc[i] = 0.f;
    #pragma unroll
    for (int n = 0; n < NB; ++n) {
        const f16x8 v8 = *(const f16x8*)(valT + base + (size_t)idx[n] * 256);
        const float w = sim[n];
        #pragma unroll
        for (int i = 0; i < 8; ++i) acc[i] = fmaf(w, (float)v8[i], acc[i]);
    }

    f16x8 h;
    #pragma unroll
    for (int i = 0; i < 8; ++i) h[i] = (_Float16)acc[i];
    *(f16x8*)(ctxT + base + (size_t)p * 256) = h;
}

extern "C" void kernel_launch(void* const* d_in, const int* in_sizes, int n_in,
                              void* d_out, int out_size, void* d_ws, size_t ws_size,
                              hipStream_t stream)
{
    (void)in_sizes; (void)n_in; (void)out_size; (void)ws_size;
    const float* x     = (const float*)d_in[0];
    const float* k1_w  = (const float*)d_in[1];
    const float* k1_b  = (const float*)d_in[2];
    const float* k1_g  = (const float*)d_in[3];
    const float* k1_be = (const float*)d_in[4];
    const float* k1_m  = (const float*)d_in[5];
    const float* k1_v  = (const float*)d_in[6];
    const float* k2_w  = (const float*)d_in[7];
    const float* k2_b  = (const float*)d_in[8];
    const float* k2_g  = (const float*)d_in[9];
    const float* k2_be = (const float*)d_in[10];
    const float* k2_m  = (const float*)d_in[11];
    const float* k2_v  = (const float*)d_in[12];
    const float* q1_w  = (const float*)d_in[13];
    const float* q1_b  = (const float*)d_in[14];
    const float* q1_g  = (const float*)d_in[15];
    const float* q1_be = (const float*)d_in[16];
    const float* q1_m  = (const float*)d_in[17];
    const float* q1_v  = (const float*)d_in[18];
    const float* q2_w  = (const float*)d_in[19];
    const float* q2_b  = (const float*)d_in[20];
    const float* q2_g  = (const float*)d_in[21];
    const float* q2_be = (const float*)d_in[22];
    const float* q2_m  = (const float*)d_in[23];
    const float* q2_v  = (const float*)d_in[24];
    const float* v_w   = (const float*)d_in[25];
    const float* v_b   = (const float*)d_in[26];
    const float* w_w   = (const float*)d_in[27];
    const float* w_b   = (const float*)d_in[28];

    _Float16* hw = (_Float16*)d_ws;
    const size_t SX = (size_t)4 * HW * 512;
    const size_t SH = (size_t)4 * HW * 256;
    _Float16* xT    = hw;
    _Float16* k1T   = xT + SX;
    _Float16* q1T   = k1T + SH;
    _Float16* valT  = q1T + SH;
    _Float16* ctxT  = valT + SH;
    _Float16* keyPC = ctxT + SH;
    _Float16* qryPC = keyPC + SH;

    GJob jv  = { xT,  v_w,  v_b,  nullptr, nullptr, nullptr, nullptr, valT,  nullptr };
    GJob jk1 = { xT,  k1_w, k1_b, k1_g, k1_be, k1_m, k1_v,            k1T,   nullptr };
    GJob jq1 = { xT,  q1_w, q1_b, q1_g, q1_be, q1_m, q1_v,            q1T,   nullptr };
    GJob jk2 = { k1T, k2_w, k2_b, k2_g, k2_be, k2_m, k2_v,            keyPC, nullptr };
    GJob jq2 = { q1T, q2_w, q2_b, q2_g, q2_be, q2_m, q2_v,            qryPC, nullptr };
    GJob jw  = { ctxT, w_w, w_b,  nullptr, nullptr, nullptr, nullptr, nullptr, (float*)d_out };

    // prep: x -> xT (b,p,c) f16
    prep_x<<<256, 256, 0, stream>>>(x, xT);
    // stage 1: {v,k1,q1} share one staged B (f16 xT); counted-vmcnt pipeline
    gemm_f<<<256, 512, 0, stream>>>(jv, jk1, jq1, 1, 512, 256, 0);
    // stage 2: k2 | q2
    gemm_f<<<256, 512, 0, stream>>>(jk2, jq2, jq2, 2, 256, 256, 0);
    // stage 3: fused sim+softmax+PV -> ctxT (p,c) f16
    attn_fused<<<dim3(512, 4), 256, 0, stream>>>(keyPC, qryPC, valT, ctxT);
    // stage 4: final conv, out f32 (b,c,p) -> d_out
    gemm_f<<<256, 512, 0, stream>>>(jw, jw, jw, 4, 256, 512, 2);
}

// Round 20
// 83.296 us; speedup vs baseline: 1.0949x; 1.0949x over previous
//
#include <hip/hip_runtime.h>

#define HW   4096
#define Hh   64
#define Ww   64
#define NB   27
#define EPSBN 1e-5f

typedef _Float16 f16x8 __attribute__((ext_vector_type(8)));
typedef _Float16 f16x4 __attribute__((ext_vector_type(4)));
typedef _Float16 f16x2 __attribute__((ext_vector_type(2)));
typedef float    f32x4 __attribute__((ext_vector_type(4)));

// async global->LDS, 16B per lane; LDS dest = wave-uniform base + lane*16
__device__ __forceinline__ void gld_lds16(const void* g, void* l) {
    __builtin_amdgcn_global_load_lds(
        (const __attribute__((address_space(1))) unsigned int*)g,
        (__attribute__((address_space(3))) unsigned int*)l, 16, 0, 0);
}

// ---------------------------------------------------------------------------
// R20 = R18 (best verified, 84.3us) + T5 s_setprio around the MFMA cluster.
// Two loop schedules:
//  * f32-B path (stage 1): single-reg-set __syncthreads loop (R16-proven).
//    (R17 lesson: 2-deep REGISTER staging -> scratch spill. R19 lesson: the
//    prep-x transpose trade LOSES ~7us - f32 reg-staging is already cheap,
//    x's redundant reads are L3-absorbed.)
//  * f16-B path (stages 2/4): counted-vmcnt pipeline via gld_lds, 3-deep B
//    (R18-proven win): issue A(t+1) regs + B(t+2) gld_lds -> MFMA(t) ->
//    WRITE_A -> asm vmcnt(4)+lgkmcnt(0) (B(t+2) stays in flight ACROSS the
//    raw s_barrier, T4) -> sched_barrier(0) (rule 18).
// T5: setprio(1) around MFMA - at 2 waves/SIMD the counted-vmcnt loop has
// wave role-diversity (one staging while the other computes), the regime
// where setprio measured +21-39% (m218b); on lockstep it is noise (m190).
// Shared-B: nA A-slots (64 rows) per staged 256px x 64k B tile. XOR swizzle
// (byte ^= (row&7)<<4) write+read. Block-uniform VALUE job selects (R3).
// mode: 0=f16 out (p,c); 2=f32 out (b,c,p).
// ---------------------------------------------------------------------------
struct GJob {
    const _Float16* in;   // (16384, K) f16, or null
    const float*    xf;   // (b,c,p) f32, or null
    const float*    w;    // (O, K) f32 original weights
    const float* b; const float* g; const float* be; const float* m; const float* v;
    _Float16* oh;
    float*    of;
};

__global__ __launch_bounds__(512, 1)
void gemm_f(GJob J0, GJob J1, GJob J2, int stage, int K, int JO, int mode)
{
    __shared__ _Float16 As[2][3][4096];   // 2 buf x 3 slots x 8KB = 48 KB
    __shared__ _Float16 Bs[3][16384];     // 3 buf x 32KB (256 px x 64 k)

    const int tid  = threadIdx.x;
    const int lane = tid & 63;
    const int w8   = tid >> 6;            // wave 0..7
    const int lr   = lane & 15;
    const int lg   = lane >> 4;
    const int wq   = w8 & 3;              // 16-row quarter of each 64-row slot
    const int ph   = w8 >> 2;             // 128-px half of the 256-px tile

    const int bid = blockIdx.x;           // 256 blocks = 1/CU
    const int xcd = bid & 7;
    const int jj  = bid >> 3;             // 0..31
    const int nb  = xcd * 8 + (jj >> 2);  // 256-px chunk 0..63 (XCD-local)
    const int u   = jj & 3;

    const int nA = (stage == 1) ? 3 : 2;
    int js0, js1, js2, ob0, ob1, ob2;
    if (stage == 1)      { js0 = 0; js1 = 1; js2 = 2; ob0 = ob1 = ob2 = u * 64; }
    else if (stage == 2) { js0 = js1 = js2 = (u >> 1); ob0 = (u & 1) * 128; ob1 = ob0 + 64; ob2 = ob1; }
    else                 { js0 = js1 = js2 = 0; ob0 = u * 128; ob1 = ob0 + 64; ob2 = ob1; }

#define JSEL(js, f) ((js) == 0 ? J0.f : ((js) == 1 ? J1.f : J2.f))
    const float* w0 = JSEL(js0, w);
    const float* w1 = JSEL(js1, w);
    const float* w2 = JSEL(js2, w);
    const float* b0 = JSEL(js0, b); const float* g0 = JSEL(js0, g);
    const float* be0 = JSEL(js0, be); const float* m0 = JSEL(js0, m); const float* v0 = JSEL(js0, v);
    const float* b1 = JSEL(js1, b); const float* g1 = JSEL(js1, g);
    const float* be1 = JSEL(js1, be); const float* m1 = JSEL(js1, m); const float* v1 = JSEL(js1, v);
    const float* b2 = JSEL(js2, b); const float* g2 = JSEL(js2, g);
    const float* be2 = JSEL(js2, be); const float* m2 = JSEL(js2, m); const float* v2 = JSEL(js2, v);
    _Float16* oh0 = JSEL(js0, oh); float* of0 = JSEL(js0, of);
    _Float16* oh1 = JSEL(js1, oh); float* of1 = JSEL(js1, of);
    _Float16* oh2 = JSEL(js2, oh); float* of2 = JSEL(js2, of);
    const _Float16* bIn = JSEL(js0, in);
    const float*    bXf = JSEL(js0, xf);
#undef JSEL

    // A f32 staging: lane covers row rowA, 8 cols at scol (pre-swizzled,
    // rule #21) -> LDS byte image identical to a gld_lds f16 path.
    const int scol = (((lane & 7) ^ (lane >> 3)) << 3);
    const int rowA = w8 * 8 + (lane >> 3);
    const float* aS0 = w0 + (size_t)(ob0 + rowA) * K + scol;
    const float* aS1 = w1 + (size_t)(ob1 + rowA) * K + scol;
    const float* aS2 = w2 + (size_t)(ob2 + rowA) * K + scol;
    const int aoffW  = w8 * 1024 + lane * 16;

    // B f16 staging (stages 2/4): wave w8 covers rows w8*32 + j*8 + lane/8
    const int rowB = w8 * 32 + (lane >> 3);
    const _Float16* bS = bIn ? (bIn + (size_t)(nb * 256 + rowB) * K + scol) : nullptr;

    // B f32 staging (stage 1): thread = one px row, 32-ch half
    const int px   = tid & 255;
    const int chh  = tid >> 8;
    const int pgS  = nb * 256 + px;
    const float* xbase = bXf ? (bXf + (size_t)(pgS >> 12) * 512 * HW + (pgS & 4095)) : nullptr;
    const int bxk  = (px & 7) << 4;
    const bool f32B = (bXf != nullptr);

    float ar0[8], ar1[8], ar2[8];              // A staging regs
    float fr[32];                              // B staging regs (stage 1 only)

    auto ISSUE_A = [&](int rd) {
        const int kb = rd * 64;
        *(float4*)&ar0[0] = *(const float4*)(aS0 + kb);
        *(float4*)&ar0[4] = *(const float4*)(aS0 + kb + 4);
        *(float4*)&ar1[0] = *(const float4*)(aS1 + kb);
        *(float4*)&ar1[4] = *(const float4*)(aS1 + kb + 4);
        if (nA > 2) {
            *(float4*)&ar2[0] = *(const float4*)(aS2 + kb);
            *(float4*)&ar2[4] = *(const float4*)(aS2 + kb + 4);
        }
    };
    auto WRITE_A = [&](int buf) {
        f16x8 h0, h1, h2;
        #pragma unroll
        for (int i2 = 0; i2 < 8; ++i2) h0[i2] = (_Float16)ar0[i2];
        #pragma unroll
        for (int i2 = 0; i2 < 8; ++i2) h1[i2] = (_Float16)ar1[i2];
        *(f16x8*)((char*)&As[buf][0][0] + aoffW) = h0;
        *(f16x8*)((char*)&As[buf][1][0] + aoffW) = h1;
        if (nA > 2) {
            #pragma unroll
            for (int i2 = 0; i2 < 8; ++i2) h2[i2] = (_Float16)ar2[i2];
            *(f16x8*)((char*)&As[buf][2][0] + aoffW) = h2;
        }
    };
    auto ISSUE_BX = [&](int rd) {
        const int cb = rd * 64 + chh * 32;
        #pragma unroll
        for (int i2 = 0; i2 < 32; ++i2)
            fr[i2] = xbase[(size_t)(cb + i2) * HW];
    };
    auto WRITE_BX = [&](int buf) {
        #pragma unroll
        for (int g4 = 0; g4 < 4; ++g4) {
            f16x8 hv;
            #pragma unroll
            for (int i2 = 0; i2 < 8; ++i2) hv[i2] = (_Float16)fr[g4 * 8 + i2];
            *(f16x8*)((char*)&Bs[buf][0] + px * 128 + ((chh * 64 + g4 * 16) ^ bxk)) = hv;
        }
    };
    auto STAGE_B16 = [&](int buf, int rd) {
        const int kb = rd * 64;
        #pragma unroll
        for (int j2 = 0; j2 < 4; ++j2)
            gld_lds16(bS + (size_t)j2 * 8 * K + kb, (char*)&Bs[buf][0] + w8 * 4096 + j2 * 1024);
    };

    f32x4 acc0[8] = {}, acc1[8] = {}, acc2[8] = {};
    const int nr = K >> 6;

    auto MFMA_TILE = [&](int bb, int ab) {
        __builtin_amdgcn_s_setprio(1);         // T5: favor MFMA-entering wave
        #pragma unroll
        for (int ks = 0; ks < 2; ++ks) {
            const int colx = (ks * 64 + lg * 16) ^ ((lr & 7) << 4);
            f16x8 bfr[8];
            #pragma unroll
            for (int t = 0; t < 8; ++t)
                bfr[t] = *(const f16x8*)((const char*)&Bs[bb][0] + (ph * 128 + t * 16 + lr) * 128 + colx);
            const int aoff = (wq * 16 + lr) * 128 + colx;
            const f16x8 af0 = *(const f16x8*)((const char*)&As[ab][0][0] + aoff);
            const f16x8 af1 = *(const f16x8*)((const char*)&As[ab][1][0] + aoff);
            #pragma unroll
            for (int t = 0; t < 8; ++t)
                acc0[t] = __builtin_amdgcn_mfma_f32_16x16x32_f16(af0, bfr[t], acc0[t], 0, 0, 0);
            #pragma unroll
            for (int t = 0; t < 8; ++t)
                acc1[t] = __builtin_amdgcn_mfma_f32_16x16x32_f16(af1, bfr[t], acc1[t], 0, 0, 0);
            if (nA > 2) {
                const f16x8 af2 = *(const f16x8*)((const char*)&As[ab][2][0] + aoff);
                #pragma unroll
                for (int t = 0; t < 8; ++t)
                    acc2[t] = __builtin_amdgcn_mfma_f32_16x16x32_f16(af2, bfr[t], acc2[t], 0, 0, 0);
            }
        }
        __builtin_amdgcn_s_setprio(0);
    };

    if (f32B) {
        // ---- stage 1: single-reg-set __syncthreads loop (proven) ----
        ISSUE_A(0);
        ISSUE_BX(0);
        WRITE_BX(0);
        WRITE_A(0);
        __syncthreads();
        int cur = 0;
        for (int rd = 0; rd < nr; ++rd) {
            const bool more = (rd + 1 < nr);
            if (more) {
                ISSUE_A(rd + 1);
                ISSUE_BX(rd + 1);          // regs; LDS writes after MFMAs
            }
            MFMA_TILE(cur, cur);
            if (more) {
                WRITE_A(cur ^ 1);
                WRITE_BX(cur ^ 1);
            }
            __syncthreads();
            cur ^= 1;
        }
    } else {
        // ---- stages 2/4: counted-vmcnt gld_lds pipeline, 3-deep B ----
        STAGE_B16(0, 0);                   // B(0) oldest
        ISSUE_A(0);
        STAGE_B16(1, 1);                   // B(1) youngest (nr>=4 always)
        WRITE_A(0);                        // compiler auto-waits ar deps
        asm volatile("s_waitcnt vmcnt(4) lgkmcnt(0)" ::: "memory");  // B(0)+A ok
        __builtin_amdgcn_s_barrier();
        __builtin_amdgcn_sched_barrier(0);

        for (int rd = 0; rd < nr; ++rd) {
            const bool m1 = (rd + 1 < nr);
            const bool m2 = (rd + 2 < nr);
            if (m1) ISSUE_A(rd + 1);
            if (m2) STAGE_B16((rd + 2) % 3, rd + 2);
            MFMA_TILE(rd % 3, rd & 1);
            if (m1) WRITE_A((rd + 1) & 1); // compiler auto-waits ar deps
            if (m2) asm volatile("s_waitcnt vmcnt(4) lgkmcnt(0)" ::: "memory");
            else    asm volatile("s_waitcnt vmcnt(0) lgkmcnt(0)" ::: "memory");
            __builtin_amdgcn_s_barrier();
            __builtin_amdgcn_sched_barrier(0);
        }
    }

    // epilogue per slot (BN fold + optional ReLU + store)
#define EPI(accS, obS, bS_, gS, beS, mS, vS, ohS, ofS) do {                      \
        const int o4 = (obS) + wq * 16 + lg * 4;                                 \
        float sc[4], off[4];                                                     \
        _Pragma("unroll")                                                        \
        for (int r = 0; r < 4; ++r) {                                            \
            const int o = o4 + r;                                                \
            if (gS) { float s = (gS)[o] * rsqrtf((vS)[o] + EPSBN);               \
                      sc[r] = s; off[r] = fmaf((bS_)[o] - (mS)[o], s, (beS)[o]); }\
            else    { sc[r] = 1.f; off[r] = (bS_)[o]; }                          \
        }                                                                        \
        _Pragma("unroll")                                                        \
        for (int t = 0; t < 8; ++t) {                                            \
            const int pg = nb * 256 + ph * 128 + t * 16 + lr;                    \
            float vv[4];                                                         \
            _Pragma("unroll")                                                    \
            for (int r = 0; r < 4; ++r) {                                        \
                float tv = fmaf(accS[t][r], sc[r], off[r]);                      \
                vv[r] = (gS) ? fmaxf(tv, 0.f) : tv;                              \
            }                                                                    \
            if (mode == 0) {                                                     \
                f16x4 hh;                                                        \
                _Pragma("unroll")                                                \
                for (int r = 0; r < 4; ++r) hh[r] = (_Float16)vv[r];             \
                *(f16x4*)((ohS) + (size_t)pg * JO + o4) = hh;                    \
            } else {                                                             \
                _Pragma("unroll")                                                \
                for (int r = 0; r < 4; ++r)                                      \
                    (ofS)[((size_t)(pg >> 12) * JO + o4 + r) * HW + (pg & 4095)] = vv[r]; \
            }                                                                    \
        }                                                                        \
    } while (0)

    EPI(acc0, ob0, b0, g0, be0, m0, v0, oh0, of0);
    EPI(acc1, ob1, b1, g1, be1, m1, v1, oh1, of1);
    if (nA > 2) EPI(acc2, ob2, b2, g2, be2, m2, v2, oh2, of2);
#undef EPI
}

// ---------------------------------------------------------------------------
// Fused attention: sim + softmax + PV, all buffers (b,p,256) f16.
// Thread = (pixel, 8-ch slot); 32 consecutive lanes read one 512B neighbor
// row coalesced. fdot2 sim partials; shfl_xor reduce over 32 slot-lanes;
// in-register softmax; OOB zeroed via valf (matches zero-padded unfold).
// ---------------------------------------------------------------------------
__global__ __launch_bounds__(256)
void attn_fused(const _Float16* __restrict__ keyT, const _Float16* __restrict__ qryT,
                const _Float16* __restrict__ valT, _Float16* __restrict__ ctxT)
{
    const int tid  = threadIdx.x;
    const int slot = tid & 31;
    const int b    = blockIdx.y;
    const int p    = blockIdx.x * 8 + (tid >> 5);
    const int y    = p >> 6;
    const int xc   = p & 63;

    int   idx[NB];
    float valf[NB];
    #pragma unroll
    for (int n = 0; n < NB; ++n) {
        const int d  = (n < 9) ? 1 : (n < 18 ? 2 : 4);
        const int i  = (n / 3) % 3 - 1;
        const int j  = n % 3 - 1;
        const int yy = y + i * d, xx = xc + j * d;
        const bool ok = ((unsigned)yy < (unsigned)Hh) && ((unsigned)xx < (unsigned)Ww);
        idx[n]  = min(max(yy, 0), Hh - 1) * Ww + min(max(xx, 0), Ww - 1);
        valf[n] = ok ? 1.f : 0.f;
    }

    const size_t base = (size_t)b * HW * 256 + slot * 8;
    const f16x8 q8 = *(const f16x8*)(qryT + base + (size_t)p * 256);

    f16x2 qp[4];
    qp[0] = __builtin_shufflevector(q8, q8, 0, 1);
    qp[1] = __builtin_shufflevector(q8, q8, 2, 3);
    qp[2] = __builtin_shufflevector(q8, q8, 4, 5);
    qp[3] = __builtin_shufflevector(q8, q8, 6, 7);

    float sim[NB];
    #pragma unroll
    for (int n = 0; n < NB; ++n) {
        const f16x8 k8 = *(const f16x8*)(keyT + base + (size_t)idx[n] * 256);
        float s = 0.f;
        s = __builtin_amdgcn_fdot2(__builtin_shufflevector(k8, k8, 0, 1), qp[0], s, false);
        s = __builtin_amdgcn_fdot2(__builtin_shufflevector(k8, k8, 2, 3), qp[1], s, false);
        s = __builtin_amdgcn_fdot2(__builtin_shufflevector(k8, k8, 4, 5), qp[2], s, false);
        s = __builtin_amdgcn_fdot2(__builtin_shufflevector(k8, k8, 6, 7), qp[3], s, false);
        sim[n] = s;
    }

    #pragma unroll
    for (int n = 0; n < NB; ++n) {
        float s = sim[n];
        s += __shfl_xor(s, 1);
        s += __shfl_xor(s, 2);
        s += __shfl_xor(s, 4);
        s += __shfl_xor(s, 8);
        s += __shfl_xor(s, 16);
        sim[n] = s * valf[n];
    }

    float mx = sim[0];
    #pragma unroll
    for (int n = 1; n < NB; ++n) mx = fmaxf(mx, sim[n]);
    float sum = 0.f;
    #pragma unroll
    for (int n = 0; n < NB; ++n) { sim[n] = __expf(sim[n] - mx); sum += sim[n]; }
    const float inv = 1.f / sum;
    #pragma unroll
    for (int n = 0; n < NB; ++n) sim[n] = sim[n] * inv * valf[n];

    float acc[8];
    #pragma unroll
    for (int i = 0; i < 8; ++i) acc[i] = 0.f;
    #pragma unroll
    for (int n = 0; n < NB; ++n) {
        const f16x8 v8 = *(const f16x8*)(valT + base + (size_t)idx[n] * 256);
        const float w = sim[n];
        #pragma unroll
        for (int i = 0; i < 8; ++i) acc[i] = fmaf(w, (float)v8[i], acc[i]);
    }

    f16x8 h;
    #pragma unroll
    for (int i = 0; i < 8; ++i) h[i] = (_Float16)acc[i];
    *(f16x8*)(ctxT + base + (size_t)p * 256) = h;
}

extern "C" void kernel_launch(void* const* d_in, const int* in_sizes, int n_in,
                              void* d_out, int out_size, void* d_ws, size_t ws_size,
                              hipStream_t stream)
{
    (void)in_sizes; (void)n_in; (void)out_size; (void)ws_size;
    const float* x     = (const float*)d_in[0];
    const float* k1_w  = (const float*)d_in[1];
    const float* k1_b  = (const float*)d_in[2];
    const float* k1_g  = (const float*)d_in[3];
    const float* k1_be = (const float*)d_in[4];
    const float* k1_m  = (const float*)d_in[5];
    const float* k1_v  = (const float*)d_in[6];
    const float* k2_w  = (const float*)d_in[7];
    const float* k2_b  = (const float*)d_in[8];
    const float* k2_g  = (const float*)d_in[9];
    const float* k2_be = (const float*)d_in[10];
    const float* k2_m  = (const float*)d_in[11];
    const float* k2_v  = (const float*)d_in[12];
    const float* q1_w  = (const float*)d_in[13];
    const float* q1_b  = (const float*)d_in[14];
    const float* q1_g  = (const float*)d_in[15];
    const float* q1_be = (const float*)d_in[16];
    const float* q1_m  = (const float*)d_in[17];
    const float* q1_v  = (const float*)d_in[18];
    const float* q2_w  = (const float*)d_in[19];
    const float* q2_b  = (const float*)d_in[20];
    const float* q2_g  = (const float*)d_in[21];
    const float* q2_be = (const float*)d_in[22];
    const float* q2_m  = (const float*)d_in[23];
    const float* q2_v  = (const float*)d_in[24];
    const float* v_w   = (const float*)d_in[25];
    const float* v_b   = (const float*)d_in[26];
    const float* w_w   = (const float*)d_in[27];
    const float* w_b   = (const float*)d_in[28];

    _Float16* hw = (_Float16*)d_ws;
    const size_t SH = (size_t)4 * HW * 256;
    _Float16* k1T   = hw;
    _Float16* q1T   = k1T + SH;
    _Float16* valT  = q1T + SH;
    _Float16* ctxT  = valT + SH;
    _Float16* keyPC = ctxT + SH;
    _Float16* qryPC = keyPC + SH;

    GJob jv  = { nullptr, x, v_w,  v_b,  nullptr, nullptr, nullptr, nullptr, valT,  nullptr };
    GJob jk1 = { nullptr, x, k1_w, k1_b, k1_g, k1_be, k1_m, k1_v,            k1T,   nullptr };
    GJob jq1 = { nullptr, x, q1_w, q1_b, q1_g, q1_be, q1_m, q1_v,            q1T,   nullptr };
    GJob jk2 = { k1T, nullptr, k2_w, k2_b, k2_g, k2_be, k2_m, k2_v,          keyPC, nullptr };
    GJob jq2 = { q1T, nullptr, q2_w, q2_b, q2_g, q2_be, q2_m, q2_v,          qryPC, nullptr };
    GJob jw  = { ctxT, nullptr, w_w, w_b,  nullptr, nullptr, nullptr, nullptr, nullptr, (float*)d_out };

    // stage 1: {v,k1,q1} share one staged B (f32 x); R16 proven loop
    gemm_f<<<256, 512, 0, stream>>>(jv, jk1, jq1, 1, 512, 256, 0);
    // stage 2: k2 | q2, counted-vmcnt gld_lds pipeline
    gemm_f<<<256, 512, 0, stream>>>(jk2, jq2, jq2, 2, 256, 256, 0);
    // stage 3: fused sim+softmax+PV -> ctxT (p,c) f16
    attn_fused<<<dim3(512, 4), 256, 0, stream>>>(keyPC, qryPC, valT, ctxT);
    // stage 4: final conv, out f32 (b,c,p) -> d_out
    gemm_f<<<256, 512, 0, stream>>>(jw, jw, jw, 4, 256, 512, 2);
}